// Round 6
// baseline (141.153 us; speedup 1.0000x reference)
//
#include <hip/hip_runtime.h>
#include <math.h>

#define D 196
#define NCH 64
#define NH 8
#define DHD 64
#define INNER 512
#define MLP 784
#define SEQ 65

__device__ __forceinline__ float bsum256(float v, float* red) {
    for (int off = 32; off > 0; off >>= 1) v += __shfl_down(v, off, 64);
    int lane = threadIdx.x & 63, wid = threadIdx.x >> 6;
    if (lane == 0) red[wid] = v;
    __syncthreads();
    float s = red[0] + red[1] + red[2] + red[3];
    __syncthreads();
    return s;
}

__device__ __forceinline__ float bsum512(float v, float* red) {
    for (int off = 32; off > 0; off >>= 1) v += __shfl_down(v, off, 64);
    int lane = threadIdx.x & 63, wid = threadIdx.x >> 6;
    if (lane == 0) red[wid] = v;
    __syncthreads();
    float s = 0.f;
#pragma unroll
    for (int i = 0; i < 8; i++) s += red[i];
    __syncthreads();
    return s;
}

// ===== K1: conv+mean (blocks 0..63) | LN1+QKV splitK4 x colpair (64..843) =====
__global__ void __launch_bounds__(256) k1(const float* __restrict__ x_pe,
        const float* __restrict__ conv_k, const float* __restrict__ bn_g,
        const float* __restrict__ bn_b, const float* __restrict__ bn_rm,
        const float* __restrict__ bn_rv, const float* __restrict__ x,
        const float* __restrict__ ln1_g, const float* __restrict__ ln1_b,
        const float* __restrict__ w_qkv,
        float* __restrict__ a, float* __restrict__ b1, float* __restrict__ qkv) {
    __shared__ float red[4];
    __shared__ float h[D];
    __shared__ float ps[512];
    int b = blockIdx.x, t = threadIdx.x;
    if (b < NCH) {
        const float* row = x_pe + b * D;
        float val = 0.f;
        if (t < D) {
            float km0 = conv_k[3], km1 = conv_k[4], km2 = conv_k[5];
            float inv = rsqrtf(bn_rv[0] + 1e-5f);
            float l = (t > 0) ? row[t - 1] : 0.f;
            float m = row[t];
            float r = (t < D - 1) ? row[t + 1] : 0.f;
            float conv = km0 * l + km1 * m + km2 * r;
            float bn = (conv - bn_rm[0]) * inv * bn_g[0] + bn_b[0];
            val = fmaxf(bn, 0.f);
            a[b * D + t] = val;
        }
        float tot = bsum256(val, red);
        if (t == 0) b1[b] = tot * (1.f / (float)D);
    } else {
        int qb = b - NCH;          // 0..779
        int n = qb / 12, cg = qb % 12;
        const float* row = x + n * D;
        float v = (t < D) ? row[t] : 0.f;
        float mean = bsum256(v, red) * (1.f / (float)D);
        float d = (t < D) ? (v - mean) : 0.f;
        float var = bsum256(d * d, red) * (1.f / (float)D);
        float rinv = rsqrtf(var + 1e-5f);
        if (t < D) h[t] = d * rinv * ln1_g[t] + ln1_b[t];
        __syncthreads();
        int qq = t >> 6, lt = t & 63;        // K quarter, col pair
        int c0 = cg * 128 + lt * 2;
        const float* wp = w_qkv + (qq * 49) * 1536 + c0;
        const float* hp = h + qq * 49;
        float a0 = 0.f, a1 = 0.f;
#pragma unroll
        for (int i = 0; i < 49; i++) {
            float2 w2 = *(const float2*)(wp + i * 1536);
            float hv = hp[i];
            a0 += hv * w2.x;
            a1 += hv * w2.y;
        }
        ps[qq * 128 + lt * 2] = a0;
        ps[qq * 128 + lt * 2 + 1] = a1;
        __syncthreads();
        if (t < 64) {
            float s0 = ps[t * 2] + ps[128 + t * 2] + ps[256 + t * 2] + ps[384 + t * 2];
            float s1 = ps[t * 2 + 1] + ps[129 + t * 2] + ps[257 + t * 2] + ps[385 + t * 2];
            *(float2*)(qkv + n * 1536 + cg * 128 + t * 2) = make_float2(s0, s1);
        }
    }
}

// ===== K2: per-row megablock: attn + outproj + gate + LN2 + FF1 + FF2 -> out =====
__global__ void __launch_bounds__(512) k2(const float* __restrict__ b1,
        const float* __restrict__ fc_w1, const float* __restrict__ fc_w2,
        const float* __restrict__ qkv, const float* __restrict__ w_out,
        const float* __restrict__ b_out, const float* __restrict__ x,
        const float* __restrict__ a, const float* __restrict__ tokens,
        const float* __restrict__ ln2_g, const float* __restrict__ ln2_b,
        const float* __restrict__ ff_w1, const float* __restrict__ ff_b1,
        const float* __restrict__ ff_w2, const float* __restrict__ ff_b2,
        float* __restrict__ out) {
    __shared__ float sq[512];
    __shared__ float so[512];
    __shared__ float pp[8 * 80];
    __shared__ float ps[784];
    __shared__ float sb1[NCH];
    __shared__ float sb2[NCH];
    __shared__ float hid[12];
    __shared__ float cn_s;
    __shared__ float x2r[200];
    __shared__ float h[200];
    __shared__ float tbr[MLP];
    __shared__ float red[8];
    int n = blockIdx.x, t = threadIdx.x;
    int w = t >> 6, L = t & 63;

    // S0: stage q row + channel means
    sq[t] = qkv[n * 1536 + t];
    if (t < NCH) sb1[t] = b1[t];
    __syncthreads();

    // S1: attention — wave w = head w
    const float scale = 0.125f;
    const float4* kr = (const float4*)(qkv + L * 1536 + INNER + w * DHD);
    const float4* q4 = (const float4*)(sq + w * DHD);
    float s = 0.f;
#pragma unroll
    for (int i = 0; i < 16; i++) {
        float4 kv = kr[i];
        float4 qv = q4[i];
        s += qv.x * kv.x + qv.y * kv.y + qv.z * kv.z + qv.w * kv.w;
    }
    float sL = s * scale;
    float t64 = sq[w * DHD + L] * qkv[64 * 1536 + INNER + w * DHD + L];
#pragma unroll
    for (int off = 1; off < 64; off <<= 1) t64 += __shfl_xor(t64, off, 64);
    float s64 = t64 * scale;
    float mx = sL;
#pragma unroll
    for (int off = 1; off < 64; off <<= 1) mx = fmaxf(mx, __shfl_xor(mx, off, 64));
    mx = fmaxf(mx, s64);
    float e = expf(sL - mx);
    float e64 = expf(s64 - mx);
    float esum = e;
#pragma unroll
    for (int off = 1; off < 64; off <<= 1) esum += __shfl_xor(esum, off, 64);
    esum += e64;
    float rs = 1.f / esum;
    pp[w * 80 + L] = e;
    if (L == 0) pp[w * 80 + 64] = e64;
    __syncthreads();
    float acc = 0.f;
#pragma unroll 13
    for (int m = 0; m < SEQ; m++)
        acc += pp[w * 80 + m] * qkv[m * 1536 + 2 * INNER + w * DHD + L];
    so[w * DHD + L] = acc * rs;
    __syncthreads();

    // S2: out-proj partials (t<392) | gate b2 (392<=t<456)
    if (t < 392) {
        int qq = t / 98, p = t - qq * 98;
        const float* wp = w_out + (qq * 128) * D + 2 * p;
        const float* op = so + qq * 128;
        float a0 = 0.f, a1 = 0.f;
#pragma unroll 16
        for (int i = 0; i < 128; i++) {
            float2 w2 = *(const float2*)(wp + i * D);
            float ov = op[i];
            a0 += ov * w2.x;
            a1 += ov * w2.y;
        }
        ps[qq * 196 + 2 * p] = a0;
        ps[qq * 196 + 2 * p + 1] = a1;
    } else if (t < 456) {
        int i = t - 392;
        float v = sb1[i];
        float gmx = -1e30f, gmn = 1e30f;
        int cle = 0, rank = 0;
        for (int j = 0; j < NCH; j++) {
            float wv = sb1[j];
            gmx = fmaxf(gmx, wv);
            gmn = fminf(gmn, wv);
            if (wv <= 0.f) cle++;
            if (wv < v || (wv == v && j < i)) rank++;
        }
        int middle;
        if (gmx < 0.f || gmn > 0.f) middle = 32;
        else if (gmx <= 0.f) middle = 0;
        else middle = cle;
        float b2v;
        if (rank < middle) {
            float ls = (float)middle;
            b2v = v - 1.f / (1.f + powf(ls, v));
        } else {
            float le = (float)(NCH - middle);
            b2v = v + 1.f / (1.f + powf(le, -v));
        }
        sb2[i] = b2v;
    }
    __syncthreads();

    // S3: hid (t<12) | x2 partial reduce (128<=t<226)
    if (t < 12) {
        float sh = 0.f;
        for (int j = 0; j < NCH; j++) sh += sb2[j] * fc_w1[j * 12 + t];
        hid[t] = fmaxf(sh, 0.f);
    } else if (t >= 128 && t < 226) {
        int p = t - 128;
        float s0 = ps[2 * p] + ps[196 + 2 * p] + ps[392 + 2 * p] + ps[588 + 2 * p];
        float s1 = ps[2 * p + 1] + ps[197 + 2 * p] + ps[393 + 2 * p] + ps[589 + 2 * p];
        float2 xr = *(const float2*)(x + n * D + 2 * p);
        float2 br = *(const float2*)(b_out + 2 * p);
        x2r[2 * p] = s0 + xr.x + br.x;
        x2r[2 * p + 1] = s1 + xr.y + br.y;
    }
    __syncthreads();

    // S4: c[n] (t==0)
    if (t == 0) {
        float sc = 0.f;
        for (int k = 0; k < 12; k++) sc += hid[k] * fc_w2[k * NCH + n];
        cn_s = 1.f / (1.f + expf(-sc));
    }
    __syncthreads();

    // S5: add x_att, LN2
    float v = 0.f;
    if (t < D) {
        float att = (n < NCH) ? a[n * D + t] * cn_s : tokens[t];
        v = x2r[t] + att;
        x2r[t] = v;
    }
    float mean = bsum512(v, red) * (1.f / (float)D);
    float d = (t < D) ? (v - mean) : 0.f;
    float var = bsum512(d * d, red) * (1.f / (float)D);
    float rinv = rsqrtf(var + 1e-5f);
    if (t < D) h[t] = d * rinv * ln2_g[t] + ln2_b[t];
    __syncthreads();

    // S6: FF1 + GELU — t<392, cols (2t, 2t+1), full K=196
    if (t < 392) {
        const float* wp = ff_w1 + 2 * t;
        float2 bb = *(const float2*)(ff_b1 + 2 * t);
        float a0 = bb.x, a1 = bb.y;
#pragma unroll 28
        for (int i = 0; i < D; i++) {
            float2 w2 = *(const float2*)(wp + i * MLP);
            float hv = h[i];
            a0 += hv * w2.x;
            a1 += hv * w2.y;
        }
        tbr[2 * t] = 0.5f * a0 * (1.f + erff(a0 * 0.70710678118f));
        tbr[2 * t + 1] = 0.5f * a1 * (1.f + erff(a1 * 0.70710678118f));
    }
    __syncthreads();

    // S7: FF2 partials — t<392: K quarter q, col pair p
    if (t < 392) {
        int qq = t / 98, p = t - qq * 98;
        const float* wp = ff_w2 + (qq * 196) * D + 2 * p;
        const float* sp = tbr + qq * 196;
        float a0 = 0.f, a1 = 0.f;
#pragma unroll 28
        for (int i = 0; i < 196; i++) {
            float2 w2 = *(const float2*)(wp + i * D);
            float sv = sp[i];
            a0 += sv * w2.x;
            a1 += sv * w2.y;
        }
        ps[qq * 196 + 2 * p] = a0;
        ps[qq * 196 + 2 * p + 1] = a1;
    }
    __syncthreads();

    // S8: reduce + bias + residual -> out
    if (t < 98) {
        float s0 = ps[2 * t] + ps[196 + 2 * t] + ps[392 + 2 * t] + ps[588 + 2 * t];
        float s1 = ps[2 * t + 1] + ps[197 + 2 * t] + ps[393 + 2 * t] + ps[589 + 2 * t];
        float2 bb = *(const float2*)(ff_b2 + 2 * t);
        float o0 = s0 + bb.x + x2r[2 * t];
        float o1 = s1 + bb.y + x2r[2 * t + 1];
        *(float2*)(out + n * D + 2 * t) = make_float2(o0, o1);
    }
}

extern "C" void kernel_launch(void* const* d_in, const int* in_sizes, int n_in,
                              void* d_out, int out_size, void* d_ws, size_t ws_size,
                              hipStream_t stream) {
    const float* x      = (const float*)d_in[0];
    const float* tokens = (const float*)d_in[1];
    const float* x_pe   = (const float*)d_in[2];
    const float* conv_k = (const float*)d_in[3];
    const float* bn_g   = (const float*)d_in[4];
    const float* bn_b   = (const float*)d_in[5];
    const float* bn_rm  = (const float*)d_in[6];
    const float* bn_rv  = (const float*)d_in[7];
    const float* fc_w1  = (const float*)d_in[8];
    const float* fc_w2  = (const float*)d_in[9];
    const float* ln1_g  = (const float*)d_in[10];
    const float* ln1_b  = (const float*)d_in[11];
    const float* ln2_g  = (const float*)d_in[12];
    const float* ln2_b  = (const float*)d_in[13];
    const float* w_qkv  = (const float*)d_in[14];
    const float* w_out  = (const float*)d_in[15];
    const float* b_out  = (const float*)d_in[16];
    const float* ff_w1  = (const float*)d_in[17];
    const float* ff_b1  = (const float*)d_in[18];
    const float* ff_w2  = (const float*)d_in[19];
    const float* ff_b2  = (const float*)d_in[20];
    float* out = (float*)d_out;

    float* ws = (float*)d_ws;
    float* a    = ws;             // 12544
    float* b1   = ws + 12544;     // 64
    float* qkv  = ws + 12608;     // 99840

    k1<<<844, 256, 0, stream>>>(x_pe, conv_k, bn_g, bn_b, bn_rm, bn_rv,
                                x, ln1_g, ln1_b, w_qkv, a, b1, qkv);
    k2<<<SEQ, 512, 0, stream>>>(b1, fc_w1, fc_w2, qkv, w_out, b_out, x, a, tokens,
                                ln2_g, ln2_b, ff_w1, ff_b1, ff_w2, ff_b2, out);
}

// Round 7
// 130.690 us; speedup vs baseline: 1.0801x; 1.0801x over previous
//
#include <hip/hip_runtime.h>
#include <math.h>

#define D 196
#define NCH 64
#define NH 8
#define DHD 64
#define INNER 512
#define MLP 784
#define SEQ 65

__device__ __forceinline__ float bsum(float v, float* red) {
    for (int off = 32; off > 0; off >>= 1) v += __shfl_down(v, off, 64);
    int lane = threadIdx.x & 63, wid = threadIdx.x >> 6;
    if (lane == 0) red[wid] = v;
    __syncthreads();
    float s = red[0] + red[1] + red[2] + red[3];
    __syncthreads();
    return s;
}

// ===== K1: conv+mean (blocks 0..63) | LN1+QKV splitK4 x float4-cols (64..453) =====
// QKV blocks: n = (b-64)/6, cg = (b-64)%6 covers cols [cg*256, cg*256+256).
// Thread t: K-quarter qq = t>>6, col-quad cq = t&63 -> cols cg*256 + cq*4 .. +3.
__global__ void __launch_bounds__(256) k1(const float* __restrict__ x_pe,
        const float* __restrict__ conv_k, const float* __restrict__ bn_g,
        const float* __restrict__ bn_b, const float* __restrict__ bn_rm,
        const float* __restrict__ bn_rv, const float* __restrict__ x,
        const float* __restrict__ ln1_g, const float* __restrict__ ln1_b,
        const float* __restrict__ w_qkv,
        float* __restrict__ a, float* __restrict__ b1, float* __restrict__ qkv) {
    __shared__ float red[4];
    __shared__ float h[D];
    __shared__ float ps[1024];
    int b = blockIdx.x, t = threadIdx.x;
    if (b < NCH) {
        const float* row = x_pe + b * D;
        float val = 0.f;
        if (t < D) {
            float km0 = conv_k[3], km1 = conv_k[4], km2 = conv_k[5];
            float inv = rsqrtf(bn_rv[0] + 1e-5f);
            float l = (t > 0) ? row[t - 1] : 0.f;
            float m = row[t];
            float r = (t < D - 1) ? row[t + 1] : 0.f;
            float conv = km0 * l + km1 * m + km2 * r;
            float bn = (conv - bn_rm[0]) * inv * bn_g[0] + bn_b[0];
            val = fmaxf(bn, 0.f);
            a[b * D + t] = val;
        }
        float tot = bsum(val, red);
        if (t == 0) b1[b] = tot * (1.f / (float)D);
    } else {
        int qb = b - NCH;          // 0..389
        int n = qb / 6, cg = qb % 6;
        const float* row = x + n * D;
        float v = (t < D) ? row[t] : 0.f;
        float mean = bsum(v, red) * (1.f / (float)D);
        float d = (t < D) ? (v - mean) : 0.f;
        float var = bsum(d * d, red) * (1.f / (float)D);
        float rinv = rsqrtf(var + 1e-5f);
        if (t < D) h[t] = d * rinv * ln1_g[t] + ln1_b[t];
        __syncthreads();
        int qq = t >> 6, cq = t & 63;        // K quarter, col quad
        int c0 = cg * 256 + cq * 4;
        const float* wp = w_qkv + (qq * 49) * 1536 + c0;
        const float* hp = h + qq * 49;
        float a0 = 0.f, a1 = 0.f, a2 = 0.f, a3 = 0.f;
#pragma unroll
        for (int i = 0; i < 49; i++) {
            float4 w4 = *(const float4*)(wp + i * 1536);
            float hv = hp[i];
            a0 += hv * w4.x;
            a1 += hv * w4.y;
            a2 += hv * w4.z;
            a3 += hv * w4.w;
        }
        float4* pq = (float4*)(ps + qq * 256 + cq * 4);
        *pq = make_float4(a0, a1, a2, a3);
        __syncthreads();
        if (t < 64) {
            float4 p0 = *(const float4*)(ps + t * 4);
            float4 p1 = *(const float4*)(ps + 256 + t * 4);
            float4 p2 = *(const float4*)(ps + 512 + t * 4);
            float4 p3 = *(const float4*)(ps + 768 + t * 4);
            float4 o4 = make_float4(p0.x + p1.x + p2.x + p3.x,
                                    p0.y + p1.y + p2.y + p3.y,
                                    p0.z + p1.z + p2.z + p3.z,
                                    p0.w + p1.w + p2.w + p3.w);
            *(float4*)(qkv + n * 1536 + cg * 256 + t * 4) = o4;
        }
    }
}

// ===== K2: attention+out-proj (blocks 0..64, 512 thr) | gate (block 65) =====
__global__ void __launch_bounds__(512) k2(const float* __restrict__ b1,
        const float* __restrict__ fc_w1, const float* __restrict__ fc_w2,
        const float* __restrict__ qkv, const float* __restrict__ w_out,
        const float* __restrict__ b_out, const float* __restrict__ x,
        float* __restrict__ c, float* __restrict__ x2) {
    int b = blockIdx.x, t = threadIdx.x;
    if (b == SEQ) {
        __shared__ float sb1[NCH];
        __shared__ float sb2[NCH];
        __shared__ float hid[12];
        if (t < NCH) sb1[t] = b1[t];
        __syncthreads();
        if (t < NCH) {
            float v = sb1[t];
            float mx = -1e30f, mn = 1e30f;
            int cle = 0, rank = 0;
            for (int j = 0; j < NCH; j++) {
                float w = sb1[j];
                mx = fmaxf(mx, w);
                mn = fminf(mn, w);
                if (w <= 0.f) cle++;
                if (w < v || (w == v && j < t)) rank++;
            }
            int middle;
            if (mx < 0.f || mn > 0.f) middle = 32;
            else if (mx <= 0.f) middle = 0;
            else middle = cle;
            float b2;
            if (rank < middle) {
                float ls = (float)middle;
                b2 = v - 1.f / (1.f + powf(ls, v));
            } else {
                float le = (float)(NCH - middle);
                b2 = v + 1.f / (1.f + powf(le, -v));
            }
            sb2[t] = b2;
        }
        __syncthreads();
        if (t < 12) {
            float s = 0.f;
            for (int j = 0; j < NCH; j++) s += sb2[j] * fc_w1[j * 12 + t];
            hid[t] = fmaxf(s, 0.f);
        }
        __syncthreads();
        if (t < NCH) {
            float s = 0.f;
            for (int k = 0; k < 12; k++) s += hid[k] * fc_w2[k * NCH + t];
            c[t] = 1.f / (1.f + expf(-s));
        }
        return;
    }
    __shared__ float sq[512];
    __shared__ float pp[8 * 80];
    __shared__ float so[512];
    __shared__ float ps[784];
    int n = b;
    int w = t >> 6, L = t & 63;
    sq[t] = qkv[n * 1536 + t];
    __syncthreads();
    const float scale = 0.125f;
    const float4* kr = (const float4*)(qkv + L * 1536 + INNER + w * DHD);
    const float4* q4 = (const float4*)(sq + w * DHD);
    float s = 0.f;
#pragma unroll
    for (int i = 0; i < 16; i++) {
        float4 kv = kr[i];
        float4 qv = q4[i];
        s += qv.x * kv.x + qv.y * kv.y + qv.z * kv.z + qv.w * kv.w;
    }
    float sL = s * scale;
    float t64 = sq[w * DHD + L] * qkv[64 * 1536 + INNER + w * DHD + L];
#pragma unroll
    for (int off = 1; off < 64; off <<= 1) t64 += __shfl_xor(t64, off, 64);
    float s64 = t64 * scale;
    float mx = sL;
#pragma unroll
    for (int off = 1; off < 64; off <<= 1) mx = fmaxf(mx, __shfl_xor(mx, off, 64));
    mx = fmaxf(mx, s64);
    float e = expf(sL - mx);
    float e64 = expf(s64 - mx);
    float esum = e;
#pragma unroll
    for (int off = 1; off < 64; off <<= 1) esum += __shfl_xor(esum, off, 64);
    esum += e64;
    float rs = 1.f / esum;
    pp[w * 80 + L] = e;
    if (L == 0) pp[w * 80 + 64] = e64;
    __syncthreads();
    float acc = 0.f;
#pragma unroll 13
    for (int m = 0; m < SEQ; m++)
        acc += pp[w * 80 + m] * qkv[m * 1536 + 2 * INNER + w * DHD + L];
    so[w * DHD + L] = acc * rs;
    __syncthreads();
    if (t < 392) {
        int qq = t / 98, p = t - qq * 98;
        const float* wp = w_out + (qq * 128) * D + 2 * p;
        const float* op = so + qq * 128;
        float a0 = 0.f, a1 = 0.f;
#pragma unroll 16
        for (int i = 0; i < 128; i++) {
            float2 w2 = *(const float2*)(wp + i * D);
            float ov = op[i];
            a0 += ov * w2.x;
            a1 += ov * w2.y;
        }
        ps[qq * 196 + 2 * p] = a0;
        ps[qq * 196 + 2 * p + 1] = a1;
    }
    __syncthreads();
    if (t < 98) {
        float s0 = ps[2 * t] + ps[196 + 2 * t] + ps[392 + 2 * t] + ps[588 + 2 * t];
        float s1 = ps[2 * t + 1] + ps[197 + 2 * t] + ps[393 + 2 * t] + ps[589 + 2 * t];
        float2 xr = *(const float2*)(x + n * D + 2 * t);
        float2 br = *(const float2*)(b_out + 2 * t);
        *(float2*)(x2 + n * D + 2 * t) = make_float2(s0 + xr.x + br.x, s1 + xr.y + br.y);
    }
}

// ===== K3: LN2(+x_att) + FF1 splitK4 x colpair + GELU, grid (65,8) =====
__global__ void __launch_bounds__(256) k3(const float* __restrict__ x2,
        const float* __restrict__ a, const float* __restrict__ c,
        const float* __restrict__ tokens,
        const float* __restrict__ ln2_g, const float* __restrict__ ln2_b,
        const float* __restrict__ ff_w1, const float* __restrict__ ff_b1,
        float* __restrict__ tb) {
    __shared__ float red[4];
    __shared__ float h[D];
    __shared__ float ps[392];
    int n = blockIdx.x, cg = blockIdx.y, t = threadIdx.x;
    float v = 0.f;
    if (t < D) {
        float att = (n < NCH) ? a[n * D + t] * c[n] : tokens[t];
        v = x2[n * D + t] + att;
    }
    float mean = bsum(v, red) * (1.f / (float)D);
    float d = (t < D) ? (v - mean) : 0.f;
    float var = bsum(d * d, red) * (1.f / (float)D);
    float rinv = rsqrtf(var + 1e-5f);
    if (t < D) h[t] = d * rinv * ln2_g[t] + ln2_b[t];
    __syncthreads();
    if (t < D) {
        int qq = t / 49, p = t - qq * 49;
        int c0 = cg * 98 + 2 * p;
        const float* wp = ff_w1 + (qq * 49) * MLP + c0;
        const float* hp = h + qq * 49;
        float a0 = 0.f, a1 = 0.f;
#pragma unroll
        for (int i = 0; i < 49; i++) {
            float2 w2 = *(const float2*)(wp + i * MLP);
            float hv = hp[i];
            a0 += hv * w2.x;
            a1 += hv * w2.y;
        }
        if (qq == 0) { a0 += ff_b1[c0]; a1 += ff_b1[c0 + 1]; }
        ps[qq * 98 + 2 * p] = a0;
        ps[qq * 98 + 2 * p + 1] = a1;
    }
    __syncthreads();
    if (t < 49) {
        float s0 = ps[2 * t] + ps[98 + 2 * t] + ps[196 + 2 * t] + ps[294 + 2 * t];
        float s1 = ps[2 * t + 1] + ps[99 + 2 * t] + ps[197 + 2 * t] + ps[295 + 2 * t];
        float g0 = 0.5f * s0 * (1.f + erff(s0 * 0.70710678118f));
        float g1 = 0.5f * s1 * (1.f + erff(s1 * 0.70710678118f));
        *(float2*)(tb + n * MLP + cg * 98 + 2 * t) = make_float2(g0, g1);
    }
}

// ===== K4: FF2 splitK8 x colpair + residual, atomicAdd into out, grid (65,8) =====
__global__ void __launch_bounds__(256) k4(const float* __restrict__ tb,
        const float* __restrict__ ff_w2, const float* __restrict__ ff_b2,
        const float* __restrict__ x2, const float* __restrict__ a,
        const float* __restrict__ c, const float* __restrict__ tokens,
        float* __restrict__ out) {
    __shared__ float st[98];
    __shared__ float ps[392];
    int n = blockIdx.x, kc = blockIdx.y, t = threadIdx.x;
    if (t < 98) st[t] = tb[n * MLP + kc * 98 + t];
    __syncthreads();
    if (t < D) {
        int hh = t / 98, p = t - hh * 98;
        const float* wp = ff_w2 + (kc * 98 + hh * 49) * D + 2 * p;
        const float* sp = st + hh * 49;
        float a0 = 0.f, a1 = 0.f;
#pragma unroll
        for (int i = 0; i < 49; i++) {
            float2 w2 = *(const float2*)(wp + i * D);
            float sv = sp[i];
            a0 += sv * w2.x;
            a1 += sv * w2.y;
        }
        ps[hh * 196 + 2 * p] = a0;
        ps[hh * 196 + 2 * p + 1] = a1;
    }
    __syncthreads();
    if (t < 98) {
        float s0 = ps[2 * t] + ps[196 + 2 * t];
        float s1 = ps[2 * t + 1] + ps[197 + 2 * t];
        if (kc == 0) {
            int c0 = 2 * t;
            float att0 = (n < NCH) ? a[n * D + c0] * c[n] : tokens[c0];
            float att1 = (n < NCH) ? a[n * D + c0 + 1] * c[n] : tokens[c0 + 1];
            s0 += ff_b2[c0] + x2[n * D + c0] + att0;
            s1 += ff_b2[c0 + 1] + x2[n * D + c0 + 1] + att1;
        }
        atomicAdd(&out[n * D + 2 * t], s0);
        atomicAdd(&out[n * D + 2 * t + 1], s1);
    }
}

// ===== K0: zero out =====
__global__ void k0(float* __restrict__ out) {
    int i = blockIdx.x * 256 + threadIdx.x;
    if (i < SEQ * D) out[i] = 0.f;
}

extern "C" void kernel_launch(void* const* d_in, const int* in_sizes, int n_in,
                              void* d_out, int out_size, void* d_ws, size_t ws_size,
                              hipStream_t stream) {
    const float* x      = (const float*)d_in[0];
    const float* tokens = (const float*)d_in[1];
    const float* x_pe   = (const float*)d_in[2];
    const float* conv_k = (const float*)d_in[3];
    const float* bn_g   = (const float*)d_in[4];
    const float* bn_b   = (const float*)d_in[5];
    const float* bn_rm  = (const float*)d_in[6];
    const float* bn_rv  = (const float*)d_in[7];
    const float* fc_w1  = (const float*)d_in[8];
    const float* fc_w2  = (const float*)d_in[9];
    const float* ln1_g  = (const float*)d_in[10];
    const float* ln1_b  = (const float*)d_in[11];
    const float* ln2_g  = (const float*)d_in[12];
    const float* ln2_b  = (const float*)d_in[13];
    const float* w_qkv  = (const float*)d_in[14];
    const float* w_out  = (const float*)d_in[15];
    const float* b_out  = (const float*)d_in[16];
    const float* ff_w1  = (const float*)d_in[17];
    const float* ff_b1  = (const float*)d_in[18];
    const float* ff_w2  = (const float*)d_in[19];
    const float* ff_b2  = (const float*)d_in[20];
    float* out = (float*)d_out;

    float* ws = (float*)d_ws;
    float* a    = ws;             // 12544
    float* b1   = ws + 12544;     // 64
    float* cc   = ws + 12608;     // 64
    float* qkv  = ws + 12672;     // 99840
    float* x2   = ws + 112512;    // 12740
    float* tb   = ws + 125252;    // 50960

    k0<<<(SEQ * D + 255) / 256, 256, 0, stream>>>(out);
    k1<<<454, 256, 0, stream>>>(x_pe, conv_k, bn_g, bn_b, bn_rm, bn_rv,
                                x, ln1_g, ln1_b, w_qkv, a, b1, qkv);
    k2<<<SEQ + 1, 512, 0, stream>>>(b1, fc_w1, fc_w2, qkv, w_out, b_out, x, cc, x2);
    k3<<<dim3(SEQ, 8), 256, 0, stream>>>(x2, a, cc, tokens, ln2_g, ln2_b,
                                         ff_w1, ff_b1, tb);
    k4<<<dim3(SEQ, 8), 256, 0, stream>>>(tb, ff_w2, ff_b2, x2, a, cc, tokens, out);
}